// Round 1
// baseline (1653.841 us; speedup 1.0000x reference)
//
#include <hip/hip_runtime.h>

// GCN layer on MI355X.
// Reference: y = x @ W^T; msgs = y[src]; out = segment_sum(msgs, dst) + bias.
// We use linearity: segment_sum(x@W^T) == segment_sum(x) @ W^T, so:
//   1) memset d_out to 0
//   2) scatter-sum x rows into d_out by dst (fp32 atomics)
//   3) in-place per-row linear: out[row] = out[row] @ W^T + bias

#define N_NODES_C 100000
#define N_EDGES_C 1600000
#define DIM 64

// ---------------------------------------------------------------------------
// Scatter: 16 threads per edge, float4 gather of x[src], 4 atomicAdds each.
// ---------------------------------------------------------------------------
__global__ void gcn_scatter_kernel(const float* __restrict__ x,
                                   const int* __restrict__ edge_index,
                                   float* __restrict__ out,
                                   int n_edges) {
    int gid = blockIdx.x * blockDim.x + threadIdx.x;
    int e = gid >> 4;            // 16 threads per edge
    if (e >= n_edges) return;
    int j = (gid & 15) << 2;     // feature offset: 0,4,...,60

    int src = edge_index[e];
    int dst = edge_index[n_edges + e];

    const float4 v = *(const float4*)(x + (size_t)src * DIM + j);
    float* o = out + (size_t)dst * DIM + j;
    atomicAdd(o + 0, v.x);
    atomicAdd(o + 1, v.y);
    atomicAdd(o + 2, v.z);
    atomicAdd(o + 3, v.w);
}

// ---------------------------------------------------------------------------
// In-place linear: each block owns 4 rows; W transposed into LDS so that
// lane i reads Wt[k*64 + i] -> bank i%32 (2-way aliasing, free on CDNA4).
// ---------------------------------------------------------------------------
__global__ void gcn_linear_inplace_kernel(float* __restrict__ out,
                                          const float* __restrict__ W,
                                          const float* __restrict__ bias,
                                          int n_nodes) {
    __shared__ float Wt[DIM * DIM];     // Wt[k*DIM+c] = W[c*DIM+k]
    __shared__ float rows[4][DIM];

    int tid = threadIdx.x;              // 256 threads
    int col = tid & 63;
    int r   = tid >> 6;                 // 0..3 local row

    // Cooperative load + transpose of W (64x64 = 16 KB)
    for (int i = tid; i < DIM * DIM; i += 256) {
        int c = i >> 6;
        int k = i & 63;
        Wt[k * DIM + c] = W[i];         // W[c][k]
    }

    int row = blockIdx.x * 4 + r;
    if (row < n_nodes) {
        rows[r][col] = out[(size_t)row * DIM + col];
    }
    __syncthreads();

    if (row < n_nodes) {
        float acc = 0.f;
        #pragma unroll
        for (int k = 0; k < DIM; ++k) {
            acc += rows[r][k] * Wt[k * DIM + col];   // rows[r][k] broadcast
        }
        out[(size_t)row * DIM + col] = acc + bias[col];
    }
}

extern "C" void kernel_launch(void* const* d_in, const int* in_sizes, int n_in,
                              void* d_out, int out_size, void* d_ws, size_t ws_size,
                              hipStream_t stream) {
    const float* x          = (const float*)d_in[0];   // [N, 64] fp32
    const float* W          = (const float*)d_in[1];   // [64, 64] fp32
    const float* bias       = (const float*)d_in[2];   // [64] fp32
    const int*   edge_index = (const int*)d_in[3];     // [2, E] int32
    // d_in[4] counts, d_in[5] out_edge_index, d_in[6] layer_i: layout hints, unused

    const int n_edges = in_sizes[3] / 2;
    const int n_nodes = in_sizes[0] / DIM;

    float* out = (float*)d_out;

    // Zero accumulator (harness poisons d_out with 0xAA before every launch)
    hipMemsetAsync(d_out, 0, (size_t)out_size * sizeof(float), stream);

    // Scatter-sum x by dst
    {
        long long total = (long long)n_edges * 16;
        int block = 256;
        int grid = (int)((total + block - 1) / block);
        gcn_scatter_kernel<<<grid, block, 0, stream>>>(x, edge_index, out, n_edges);
    }

    // In-place linear transform + bias
    {
        int block = 256;
        int grid = (n_nodes + 3) / 4;
        gcn_linear_inplace_kernel<<<grid, block, 0, stream>>>(out, W, bias, n_nodes);
    }
}

// Round 2
// 519.255 us; speedup vs baseline: 3.1850x; 3.1850x over previous
//
#include <hip/hip_runtime.h>

// GCN layer, pull-based:
//   segment_sum(x@W^T)[dst] == segment_sum(x)[dst] @ W^T  (linearity)
// Pipeline:
//   1) histogram dst -> counts               (1.6M int atomics)
//   2) exclusive scan -> offsets, cursor     (single 1024-thread block)
//   3) fill: srcs_sorted[cursor[dst]++]=src  (1.6M int atomics)
//   4) gather+linear: wave per node, acc in regs, W row per lane in VGPRs,
//      cross-lane row broadcast via v_readlane (no LDS, no output atomics)
// Fallback (ws too small): round-1 atomic scatter + LDS linear.

#define DIM 64

// ---------------------------------------------------------------------------
__global__ void hist_kernel(const int* __restrict__ ei, int* __restrict__ counts,
                            int E) {
    int e = blockIdx.x * blockDim.x + threadIdx.x;
    if (e < E) atomicAdd(&counts[ei[E + e]], 1);
}

// Single-block exclusive scan over n counts -> offsets[n+1], cursor[n].
__global__ void scan_kernel(const int* __restrict__ counts,
                            int* __restrict__ offsets,
                            int* __restrict__ cursor, int n) {
    __shared__ int wsums[16];
    __shared__ int carry_s;
    __shared__ int wtotal_s;
    const int tid = threadIdx.x;            // 1024
    const int lane = tid & 63;
    const int w = tid >> 6;

    if (tid == 0) carry_s = 0;
    __syncthreads();

    for (int base = 0; base < n; base += 1024) {
        int i = base + tid;
        int v = (i < n) ? counts[i] : 0;

        // wave-inclusive scan
        int incl = v;
        #pragma unroll
        for (int d = 1; d < 64; d <<= 1) {
            int t = __shfl_up(incl, d, 64);
            if (lane >= d) incl += t;
        }
        if (lane == 63) wsums[w] = incl;
        __syncthreads();                     // S1
        if (tid == 0) {
            int run = 0;
            #pragma unroll
            for (int j = 0; j < 16; ++j) { int t = wsums[j]; wsums[j] = run; run += t; }
            wtotal_s = run;
        }
        __syncthreads();                     // S2
        int chunk_incl = incl + wsums[w];
        int excl = chunk_incl - v;
        int carry = carry_s;
        if (i < n) {
            offsets[i] = carry + excl;
            cursor[i]  = carry + excl;
        }
        __syncthreads();                     // S3: all read carry_s
        if (tid == 0) carry_s = carry + wtotal_s;
        __syncthreads();                     // S4: update visible
    }
    if (tid == 0) offsets[n] = carry_s;
}

__global__ void fill_kernel(const int* __restrict__ ei, int* __restrict__ cursor,
                            int* __restrict__ srcs, int E) {
    int e = blockIdx.x * blockDim.x + threadIdx.x;
    if (e < E) {
        int d = ei[E + e];
        int p = atomicAdd(&cursor[d], 1);
        srcs[p] = ei[e];
    }
}

// ---------------------------------------------------------------------------
// One wave per node (grid-stride). Lane c holds W row c (64 VGPRs).
// out[node][c] = bias[c] + sum_k acc[k] * W[c][k], acc[k] broadcast by readlane.
__global__ __launch_bounds__(256) void gather_linear_kernel(
        const float* __restrict__ x, const int* __restrict__ offsets,
        const int* __restrict__ srcs, const float* __restrict__ W,
        const float* __restrict__ bias, float* __restrict__ out, int n_nodes) {
    const int lane = threadIdx.x & 63;
    const int gwave = (blockIdx.x * blockDim.x + threadIdx.x) >> 6;
    const int total_waves = (gridDim.x * blockDim.x) >> 6;

    // W row `lane`, contiguous 256 B per lane
    float wv[DIM];
    #pragma unroll
    for (int k4 = 0; k4 < DIM / 4; ++k4) {
        float4 t = *(const float4*)(W + (size_t)lane * DIM + k4 * 4);
        wv[k4 * 4 + 0] = t.x; wv[k4 * 4 + 1] = t.y;
        wv[k4 * 4 + 2] = t.z; wv[k4 * 4 + 3] = t.w;
    }
    const float b = bias[lane];

    for (int node = gwave; node < n_nodes; node += total_waves) {
        int beg = offsets[node];
        int end = offsets[node + 1];

        float a0 = 0.f, a1 = 0.f, a2 = 0.f, a3 = 0.f;
        int i = beg;
        for (; i + 3 < end; i += 4) {   // 4-wide MLP
            int s0 = srcs[i], s1 = srcs[i + 1], s2 = srcs[i + 2], s3 = srcs[i + 3];
            a0 += x[(size_t)s0 * DIM + lane];
            a1 += x[(size_t)s1 * DIM + lane];
            a2 += x[(size_t)s2 * DIM + lane];
            a3 += x[(size_t)s3 * DIM + lane];
        }
        for (; i < end; ++i) a0 += x[(size_t)srcs[i] * DIM + lane];
        float acc = (a0 + a1) + (a2 + a3);

        float r = b;
        #pragma unroll
        for (int k = 0; k < DIM; ++k) {
            float rv = __int_as_float(
                __builtin_amdgcn_readlane(__float_as_int(acc), k));
            r += rv * wv[k];
        }
        out[(size_t)node * DIM + lane] = r;
    }
}

// ---------------------------------------------------------------------------
// Fallback path (round-1): atomic scatter + LDS linear.
__global__ void gcn_scatter_kernel(const float* __restrict__ x,
                                   const int* __restrict__ edge_index,
                                   float* __restrict__ out, int n_edges) {
    int gid = blockIdx.x * blockDim.x + threadIdx.x;
    int e = gid >> 4;
    if (e >= n_edges) return;
    int j = (gid & 15) << 2;
    int src = edge_index[e];
    int dst = edge_index[n_edges + e];
    const float4 v = *(const float4*)(x + (size_t)src * DIM + j);
    float* o = out + (size_t)dst * DIM + j;
    atomicAdd(o + 0, v.x); atomicAdd(o + 1, v.y);
    atomicAdd(o + 2, v.z); atomicAdd(o + 3, v.w);
}

__global__ void gcn_linear_inplace_kernel(float* __restrict__ out,
                                          const float* __restrict__ W,
                                          const float* __restrict__ bias,
                                          int n_nodes) {
    __shared__ float Wt[DIM * DIM];
    __shared__ float rows[4][DIM];
    int tid = threadIdx.x;
    int col = tid & 63;
    int r = tid >> 6;
    for (int i = tid; i < DIM * DIM; i += 256) {
        int c = i >> 6, k = i & 63;
        Wt[k * DIM + c] = W[i];
    }
    int row = blockIdx.x * 4 + r;
    if (row < n_nodes) rows[r][col] = out[(size_t)row * DIM + col];
    __syncthreads();
    if (row < n_nodes) {
        float acc = 0.f;
        #pragma unroll
        for (int k = 0; k < DIM; ++k) acc += rows[r][k] * Wt[k * DIM + col];
        out[(size_t)row * DIM + col] = acc + bias[col];
    }
}

// ---------------------------------------------------------------------------
extern "C" void kernel_launch(void* const* d_in, const int* in_sizes, int n_in,
                              void* d_out, int out_size, void* d_ws, size_t ws_size,
                              hipStream_t stream) {
    const float* x          = (const float*)d_in[0];   // [N, 64]
    const float* W          = (const float*)d_in[1];   // [64, 64]
    const float* bias       = (const float*)d_in[2];   // [64]
    const int*   edge_index = (const int*)d_in[3];     // [2, E]

    const int E = in_sizes[3] / 2;
    const int N = in_sizes[0] / DIM;
    float* out = (float*)d_out;

    const size_t need = ((size_t)3 * N + 1 + E) * sizeof(int);
    if (ws_size >= need) {
        int* counts  = (int*)d_ws;              // [N]
        int* offsets = counts + N;              // [N+1]
        int* cursor  = offsets + N + 1;         // [N]
        int* srcs    = cursor + N;              // [E]

        hipMemsetAsync(counts, 0, (size_t)N * sizeof(int), stream);

        int block = 256;
        int egrid = (E + block - 1) / block;
        hist_kernel<<<egrid, block, 0, stream>>>(edge_index, counts, E);
        scan_kernel<<<1, 1024, 0, stream>>>(counts, offsets, cursor, N);
        fill_kernel<<<egrid, block, 0, stream>>>(edge_index, cursor, srcs, E);

        gather_linear_kernel<<<1536, 256, 0, stream>>>(
            x, offsets, srcs, W, bias, out, N);
    } else {
        // Fallback: atomic scatter path
        hipMemsetAsync(d_out, 0, (size_t)out_size * sizeof(float), stream);
        long long total = (long long)E * 16;
        int block = 256;
        int grid = (int)((total + block - 1) / block);
        gcn_scatter_kernel<<<grid, block, 0, stream>>>(x, edge_index, out, E);
        int lgrid = (N + 3) / 4;
        gcn_linear_inplace_kernel<<<lgrid, 256, 0, stream>>>(out, W, bias, N);
    }
}

// Round 3
// 435.516 us; speedup vs baseline: 3.7974x; 1.1923x over previous
//
#include <hip/hip_runtime.h>

// GCN layer, pull-based with parallel CSR build:
//   segment_sum(x@W^T)[dst] == segment_sum(x)[dst] @ W^T  (linearity)
// Pipeline:
//   1) hist: histogram dst -> counts                (1.6M int atomics)
//   2) scan (3-pass parallel): counts -> offsets, cursor
//   3) fill: srcs[cursor[dst]++] = src              (1.6M int atomics)
//   4) gather+linear: wave per ~8 nodes, 8-wide edge unroll (ILP for L3
//      latency), W row per lane in VGPRs, readlane broadcast epilogue.

#define DIM 64
#define SCAN_BLOCKS 256

// ---------------------------------------------------------------------------
__global__ void hist_kernel(const int* __restrict__ ei, int* __restrict__ counts,
                            int E) {
    int e = blockIdx.x * blockDim.x + threadIdx.x;
    if (e < E) atomicAdd(&counts[ei[E + e]], 1);
}

// Pass A: per-block reduction of a contiguous chunk of counts.
__global__ void scan_reduce_kernel(const int* __restrict__ counts,
                                   int* __restrict__ bsum, int N, int chunk) {
    __shared__ int ws[4];
    int b = blockIdx.x, t = threadIdx.x;
    int base = b * chunk;
    int lim = min(base + chunk, N);
    int sum = 0;
    for (int i = base + t; i < lim; i += 256) sum += counts[i];
    #pragma unroll
    for (int d = 32; d; d >>= 1) sum += __shfl_down(sum, d, 64);
    if ((t & 63) == 0) ws[t >> 6] = sum;
    __syncthreads();
    if (t == 0) bsum[b] = ws[0] + ws[1] + ws[2] + ws[3];
}

// Pass B: single block scans the 256 block partials; writes offsets[N]=total.
__global__ void scan_partials_kernel(const int* __restrict__ bsum,
                                     int* __restrict__ bpre,
                                     int* __restrict__ offsets, int N) {
    __shared__ int tmp[SCAN_BLOCKS];
    int t = threadIdx.x;
    int v = bsum[t];
    tmp[t] = v;
    __syncthreads();
    #pragma unroll
    for (int d = 1; d < SCAN_BLOCKS; d <<= 1) {
        int u = (t >= d) ? tmp[t - d] : 0;
        __syncthreads();
        tmp[t] += u;
        __syncthreads();
    }
    bpre[t] = tmp[t] - v;                    // exclusive
    if (t == SCAN_BLOCKS - 1) offsets[N] = tmp[t];
}

// Pass C: per-block scan of its chunk + block prefix -> offsets & cursor.
__global__ void scan_write_kernel(const int* __restrict__ counts,
                                  const int* __restrict__ bpre,
                                  int* __restrict__ offsets,
                                  int* __restrict__ cursor, int N, int chunk) {
    __shared__ int tmp[256];
    int b = blockIdx.x, t = threadIdx.x;
    int base = b * chunk;
    int lim = min(base + chunk, N);
    int carry = bpre[b];
    for (int tile = base; tile < lim; tile += 256) {
        int i = tile + t;
        int v = (i < lim) ? counts[i] : 0;
        tmp[t] = v;
        __syncthreads();
        #pragma unroll
        for (int d = 1; d < 256; d <<= 1) {
            int u = (t >= d) ? tmp[t - d] : 0;
            __syncthreads();
            tmp[t] += u;
            __syncthreads();
        }
        int excl = tmp[t] - v;
        if (i < lim) { offsets[i] = carry + excl; cursor[i] = carry + excl; }
        int total = tmp[255];
        __syncthreads();                     // protect tmp before next tile
        carry += total;
    }
}

__global__ void fill_kernel(const int* __restrict__ ei, int* __restrict__ cursor,
                            int* __restrict__ srcs, int E) {
    int e = blockIdx.x * blockDim.x + threadIdx.x;
    if (e < E) {
        int d = ei[E + e];
        int p = atomicAdd(&cursor[d], 1);
        srcs[p] = ei[e];
    }
}

// ---------------------------------------------------------------------------
// Wave per ~8 nodes (grid-stride). Lane c holds W row c in VGPRs.
// 8-wide edge unroll => 8 independent 256B row loads in flight per wave.
__global__ __launch_bounds__(256) void gather_linear_kernel(
        const float* __restrict__ x, const int* __restrict__ offsets,
        const int* __restrict__ srcs, const float* __restrict__ W,
        const float* __restrict__ bias, float* __restrict__ out, int n_nodes) {
    const int lane = threadIdx.x & 63;
    const int gwave = (blockIdx.x * blockDim.x + threadIdx.x) >> 6;
    const int total_waves = (gridDim.x * blockDim.x) >> 6;

    float wv[DIM];
    #pragma unroll
    for (int k4 = 0; k4 < DIM / 4; ++k4) {
        float4 t = *(const float4*)(W + (size_t)lane * DIM + k4 * 4);
        wv[k4 * 4 + 0] = t.x; wv[k4 * 4 + 1] = t.y;
        wv[k4 * 4 + 2] = t.z; wv[k4 * 4 + 3] = t.w;
    }
    const float b = bias[lane];

    for (int node = gwave; node < n_nodes; node += total_waves) {
        int beg = offsets[node];
        int end = offsets[node + 1];

        float a0 = 0.f, a1 = 0.f, a2 = 0.f, a3 = 0.f;
        float a4 = 0.f, a5 = 0.f, a6 = 0.f, a7 = 0.f;
        int i = beg;
        for (; i + 8 <= end; i += 8) {
            int s0 = srcs[i + 0], s1 = srcs[i + 1];
            int s2 = srcs[i + 2], s3 = srcs[i + 3];
            int s4 = srcs[i + 4], s5 = srcs[i + 5];
            int s6 = srcs[i + 6], s7 = srcs[i + 7];
            a0 += x[(size_t)s0 * DIM + lane];
            a1 += x[(size_t)s1 * DIM + lane];
            a2 += x[(size_t)s2 * DIM + lane];
            a3 += x[(size_t)s3 * DIM + lane];
            a4 += x[(size_t)s4 * DIM + lane];
            a5 += x[(size_t)s5 * DIM + lane];
            a6 += x[(size_t)s6 * DIM + lane];
            a7 += x[(size_t)s7 * DIM + lane];
        }
        for (; i < end; ++i) a0 += x[(size_t)srcs[i] * DIM + lane];
        float acc = ((a0 + a1) + (a2 + a3)) + ((a4 + a5) + (a6 + a7));

        // out[node][lane] = b + sum_k acc_bcast(k) * W[lane][k], 4 chains
        float r0 = b, r1 = 0.f, r2 = 0.f, r3 = 0.f;
        #pragma unroll
        for (int k = 0; k < DIM; k += 4) {
            r0 += __int_as_float(__builtin_amdgcn_readlane(__float_as_int(acc), k + 0)) * wv[k + 0];
            r1 += __int_as_float(__builtin_amdgcn_readlane(__float_as_int(acc), k + 1)) * wv[k + 1];
            r2 += __int_as_float(__builtin_amdgcn_readlane(__float_as_int(acc), k + 2)) * wv[k + 2];
            r3 += __int_as_float(__builtin_amdgcn_readlane(__float_as_int(acc), k + 3)) * wv[k + 3];
        }
        out[(size_t)node * DIM + lane] = (r0 + r1) + (r2 + r3);
    }
}

// ---------------------------------------------------------------------------
// Fallback path: atomic scatter + LDS linear (used only if ws too small).
__global__ void gcn_scatter_kernel(const float* __restrict__ x,
                                   const int* __restrict__ edge_index,
                                   float* __restrict__ out, int n_edges) {
    int gid = blockIdx.x * blockDim.x + threadIdx.x;
    int e = gid >> 4;
    if (e >= n_edges) return;
    int j = (gid & 15) << 2;
    int src = edge_index[e];
    int dst = edge_index[n_edges + e];
    const float4 v = *(const float4*)(x + (size_t)src * DIM + j);
    float* o = out + (size_t)dst * DIM + j;
    atomicAdd(o + 0, v.x); atomicAdd(o + 1, v.y);
    atomicAdd(o + 2, v.z); atomicAdd(o + 3, v.w);
}

__global__ void gcn_linear_inplace_kernel(float* __restrict__ out,
                                          const float* __restrict__ W,
                                          const float* __restrict__ bias,
                                          int n_nodes) {
    __shared__ float Wt[DIM * DIM];
    __shared__ float rows[4][DIM];
    int tid = threadIdx.x;
    int col = tid & 63;
    int r = tid >> 6;
    for (int i = tid; i < DIM * DIM; i += 256) {
        int c = i >> 6, k = i & 63;
        Wt[k * DIM + c] = W[i];
    }
    int row = blockIdx.x * 4 + r;
    if (row < n_nodes) rows[r][col] = out[(size_t)row * DIM + col];
    __syncthreads();
    if (row < n_nodes) {
        float acc = 0.f;
        #pragma unroll
        for (int k = 0; k < DIM; ++k) acc += rows[r][k] * Wt[k * DIM + col];
        out[(size_t)row * DIM + col] = acc + bias[col];
    }
}

// ---------------------------------------------------------------------------
extern "C" void kernel_launch(void* const* d_in, const int* in_sizes, int n_in,
                              void* d_out, int out_size, void* d_ws, size_t ws_size,
                              hipStream_t stream) {
    const float* x          = (const float*)d_in[0];   // [N, 64]
    const float* W          = (const float*)d_in[1];   // [64, 64]
    const float* bias       = (const float*)d_in[2];   // [64]
    const int*   edge_index = (const int*)d_in[3];     // [2, E]

    const int E = in_sizes[3] / 2;
    const int N = in_sizes[0] / DIM;
    float* out = (float*)d_out;

    const size_t need = ((size_t)3 * N + 1 + E + 2 * SCAN_BLOCKS) * sizeof(int);
    if (ws_size >= need) {
        int* counts  = (int*)d_ws;              // [N]
        int* offsets = counts + N;              // [N+1]
        int* cursor  = offsets + N + 1;         // [N]
        int* srcs    = cursor + N;              // [E]
        int* bsum    = srcs + E;                // [SCAN_BLOCKS]
        int* bpre    = bsum + SCAN_BLOCKS;      // [SCAN_BLOCKS]

        hipMemsetAsync(counts, 0, (size_t)N * sizeof(int), stream);

        const int block = 256;
        const int egrid = (E + block - 1) / block;
        const int chunk = (N + SCAN_BLOCKS - 1) / SCAN_BLOCKS;

        hist_kernel<<<egrid, block, 0, stream>>>(edge_index, counts, E);
        scan_reduce_kernel<<<SCAN_BLOCKS, block, 0, stream>>>(counts, bsum, N, chunk);
        scan_partials_kernel<<<1, SCAN_BLOCKS, 0, stream>>>(bsum, bpre, offsets, N);
        scan_write_kernel<<<SCAN_BLOCKS, block, 0, stream>>>(counts, bpre, offsets,
                                                             cursor, N, chunk);
        fill_kernel<<<egrid, block, 0, stream>>>(edge_index, cursor, srcs, E);

        // ~8 nodes per wave
        int waves = (N + 7) / 8;
        int ggrid = (waves + 3) / 4;
        gather_linear_kernel<<<ggrid, block, 0, stream>>>(
            x, offsets, srcs, W, bias, out, N);
    } else {
        hipMemsetAsync(d_out, 0, (size_t)out_size * sizeof(float), stream);
        long long total = (long long)E * 16;
        int block = 256;
        int grid = (int)((total + block - 1) / block);
        gcn_scatter_kernel<<<grid, block, 0, stream>>>(x, edge_index, out, E);
        int lgrid = (N + 3) / 4;
        gcn_linear_inplace_kernel<<<lgrid, 256, 0, stream>>>(out, W, bias, N);
    }
}